// Round 6
// baseline (235.451 us; speedup 1.0000x reference)
//
#include <hip/hip_runtime.h>
#include <hip/hip_bf16.h>
#include <stdint.h>

typedef __bf16 bf16x8 __attribute__((ext_vector_type(8)));
typedef __bf16 bf16x4 __attribute__((ext_vector_type(4)));
typedef float f32x4 __attribute__((ext_vector_type(4)));

#define DMODEL 1024
#define SEQ    2048
#define NHEAD  16
#define DK     64
#define MTOT   4096
#define KDIM   1024

// Explicit ISA-level drain before barriers that close a staging protocol
// (round-4 post-timing divergence fix; measured free).
#define DRAIN_VM_LGKM() asm volatile("s_waitcnt vmcnt(0) lgkmcnt(0)" ::: "memory")
#define DRAIN_LGKM()    asm volatile("s_waitcnt lgkmcnt(0)" ::: "memory")

__device__ __forceinline__ void gl2lds16(const void* g, void* l) {
  __builtin_amdgcn_global_load_lds((__attribute__((address_space(1))) void*)(g),
                                   (__attribute__((address_space(3))) void*)(l),
                                   16, 0, 0);
}

// ---------------- prep: f32 -> bf16 convert, q/k/v batched ----------------
__global__ __launch_bounds__(256) void k_cvt3(const float* __restrict__ q,
                                              const float* __restrict__ k,
                                              const float* __restrict__ v,
                                              __bf16* __restrict__ oq,
                                              __bf16* __restrict__ ok,
                                              __bf16* __restrict__ ov,
                                              int n4) {
  const int which = blockIdx.y;
  const float* in = which == 0 ? q : (which == 1 ? k : v);
  __bf16* out = which == 0 ? oq : (which == 1 ? ok : ov);
  const int i = blockIdx.x * 256 + threadIdx.x;
  if (i >= n4) return;
  const float4 f = ((const float4*)in)[i];
  bf16x4 o = { (__bf16)f.x, (__bf16)f.y, (__bf16)f.z, (__bf16)f.w };
  ((bf16x4*)out)[i] = o;
}

// ---------------- prep: W [K][N] f32 -> WT [N][K] bf16, 4 weights batched ----------------
__global__ __launch_bounds__(256) void k_transpose4(const float* __restrict__ w0,
                                                    const float* __restrict__ w1,
                                                    const float* __restrict__ w2,
                                                    const float* __restrict__ w3,
                                                    __bf16* __restrict__ t0,
                                                    __bf16* __restrict__ t1,
                                                    __bf16* __restrict__ t2,
                                                    __bf16* __restrict__ t3) {
  const int z = blockIdx.z;
  const float* W = z == 0 ? w0 : (z == 1 ? w1 : (z == 2 ? w2 : w3));
  __bf16* WT = z == 0 ? t0 : (z == 1 ? t1 : (z == 2 ? t2 : t3));
  __shared__ float tile[32][33];
  int n0 = blockIdx.x * 32, k0 = blockIdx.y * 32;
  int tx = threadIdx.x & 31, ty = threadIdx.x >> 5;
  #pragma unroll
  for (int i = ty; i < 32; i += 8)
    tile[i][tx] = W[(size_t)(k0 + i) * DMODEL + n0 + tx];
  __syncthreads();
  #pragma unroll
  for (int i = ty; i < 32; i += 8)
    WT[(size_t)(n0 + i) * DMODEL + k0 + tx] = (__bf16)tile[tx][i];
}

// ---------------- batched projection GEMM: z in {q,k,v} ----------------
__global__ __launch_bounds__(256) void k_gemm_qkv(
    const __bf16* __restrict__ A0, const __bf16* __restrict__ A1, const __bf16* __restrict__ A2,
    const __bf16* __restrict__ W0, const __bf16* __restrict__ W1, const __bf16* __restrict__ W2,
    const float* __restrict__ bi0, const float* __restrict__ bi1, const float* __restrict__ bi2,
    __bf16* __restrict__ C0, __bf16* __restrict__ C1, __bf16* __restrict__ C2) {
  const int z = blockIdx.z;
  const __bf16* A  = z == 0 ? A0 : (z == 1 ? A1 : A2);
  const __bf16* BT = z == 0 ? W0 : (z == 1 ? W1 : W2);
  const float* bias = z == 0 ? bi0 : (z == 1 ? bi1 : bi2);
  __bf16* Cout = z == 0 ? C0 : (z == 1 ? C1 : C2);

  __shared__ __align__(16) __bf16 As[128 * 32];
  __shared__ __align__(16) __bf16 Bs[128 * 32];
  const int tid = threadIdx.x;
  const int lane = tid & 63;
  const int wv = tid >> 6;
  const int wm = wv >> 1, wn = wv & 1;
  const int m0 = blockIdx.y * 128, n0 = blockIdx.x * 128;
  const int lr = lane & 15, lg = lane >> 4;

  f32x4 acc[4][4] = {};

  for (int k0 = 0; k0 < KDIM; k0 += 32) {
    #pragma unroll
    for (int i = 0; i < 2; ++i) {
      int c = tid + i * 256;
      int row = c >> 2, seg = c & 3;
      gl2lds16(A + (size_t)(m0 + row) * KDIM + k0 + seg * 8, (char*)As + c * 16);
      gl2lds16(BT + (size_t)(n0 + row) * KDIM + k0 + seg * 8, (char*)Bs + c * 16);
    }
    DRAIN_VM_LGKM();
    __syncthreads();
    bf16x8 af[4], bfr[4];
    #pragma unroll
    for (int mi = 0; mi < 4; ++mi)
      af[mi] = *(const bf16x8*)&As[(wm * 64 + mi * 16 + lr) * 32 + lg * 8];
    #pragma unroll
    for (int ni = 0; ni < 4; ++ni)
      bfr[ni] = *(const bf16x8*)&Bs[(wn * 64 + ni * 16 + lr) * 32 + lg * 8];
    #pragma unroll
    for (int mi = 0; mi < 4; ++mi)
      #pragma unroll
      for (int ni = 0; ni < 4; ++ni)
        acc[mi][ni] = __builtin_amdgcn_mfma_f32_16x16x32_bf16(af[mi], bfr[ni], acc[mi][ni], 0, 0, 0);
    DRAIN_LGKM();
    __syncthreads();
  }

  #pragma unroll
  for (int mi = 0; mi < 4; ++mi)
    #pragma unroll
    for (int ni = 0; ni < 4; ++ni) {
      const int col = n0 + wn * 64 + ni * 16 + lr;
      const float bv = bias[col];
      #pragma unroll
      for (int r = 0; r < 4; ++r) {
        const int row = m0 + wm * 64 + mi * 16 + lg * 4 + r;
        float v = acc[mi][ni][r] + bv;
        const int b = row >> 11, s = row & (SEQ - 1);
        const int h = col >> 6, dd = col & (DK - 1);
        if (z == 2)
          Cout[((size_t)(b * NHEAD + h) * DK + dd) * SEQ + s] = (__bf16)v;
        else
          Cout[((size_t)(b * NHEAD + h) * SEQ + s) * DK + dd] = (__bf16)v;
      }
    }
}

// ---------------- final GEMM: f32 out + bias ----------------
__global__ __launch_bounds__(256) void k_gemm_out(const __bf16* __restrict__ A,
                                                  const __bf16* __restrict__ BT,
                                                  const float* __restrict__ bias,
                                                  float* __restrict__ Cout) {
  __shared__ __align__(16) __bf16 As[128 * 32];
  __shared__ __align__(16) __bf16 Bs[128 * 32];
  const int tid = threadIdx.x;
  const int lane = tid & 63;
  const int wv = tid >> 6;
  const int wm = wv >> 1, wn = wv & 1;
  const int m0 = blockIdx.y * 128, n0 = blockIdx.x * 128;
  const int lr = lane & 15, lg = lane >> 4;

  f32x4 acc[4][4] = {};

  for (int k0 = 0; k0 < KDIM; k0 += 32) {
    #pragma unroll
    for (int i = 0; i < 2; ++i) {
      int c = tid + i * 256;
      int row = c >> 2, seg = c & 3;
      gl2lds16(A + (size_t)(m0 + row) * KDIM + k0 + seg * 8, (char*)As + c * 16);
      gl2lds16(BT + (size_t)(n0 + row) * KDIM + k0 + seg * 8, (char*)Bs + c * 16);
    }
    DRAIN_VM_LGKM();
    __syncthreads();
    bf16x8 af[4], bfr[4];
    #pragma unroll
    for (int mi = 0; mi < 4; ++mi)
      af[mi] = *(const bf16x8*)&As[(wm * 64 + mi * 16 + lr) * 32 + lg * 8];
    #pragma unroll
    for (int ni = 0; ni < 4; ++ni)
      bfr[ni] = *(const bf16x8*)&Bs[(wn * 64 + ni * 16 + lr) * 32 + lg * 8];
    #pragma unroll
    for (int mi = 0; mi < 4; ++mi)
      #pragma unroll
      for (int ni = 0; ni < 4; ++ni)
        acc[mi][ni] = __builtin_amdgcn_mfma_f32_16x16x32_bf16(af[mi], bfr[ni], acc[mi][ni], 0, 0, 0);
    DRAIN_LGKM();
    __syncthreads();
  }

  #pragma unroll
  for (int mi = 0; mi < 4; ++mi)
    #pragma unroll
    for (int ni = 0; ni < 4; ++ni) {
      const int col = n0 + wn * 64 + ni * 16 + lr;
      const float bv = bias[col];
      #pragma unroll
      for (int r = 0; r < 4; ++r) {
        const int row = m0 + wm * 64 + mi * 16 + lg * 4 + r;
        Cout[(size_t)row * DMODEL + col] = acc[mi][ni][r] + bv;
      }
    }
}

// ---------------- flash attention (causal): barrier-free single-wave blocks ----------------
// Q,K: [B,H,S,DK]  V: [B,H,DK,S]  O: [B,S,D] bf16
// One wave per block owning 32 Q rows (two 16-row MFMA groups sharing K/V
// fragments). K/V read DIRECTLY from global (L2-resident: XCD-pinned, 4 bh x
// 512KB = 2MB < 4MB L2) -- no staging, no __syncthreads, no convoy. 2048
// blocks (8/CU work units) + launch_bounds(64,4) (<=128 VGPR -> 16 waves/CU
// resident): HW scheduler backfills small causal blocks behind big ones (LPT
// dispatch order). Swapped QK^T: lane owns q-rows lr and 16+lr -> softmax is
// in-register + 2 shfl per row-group. P round-trip in wave-private LDS.
__global__ __launch_bounds__(64, 4) void k_attn(const __bf16* __restrict__ Q,
                                                const __bf16* __restrict__ Kt,
                                                const __bf16* __restrict__ Vt,
                                                const float* __restrict__ pmask,
                                                __bf16* __restrict__ O) {
  __shared__ __align__(16) __bf16 plds[32 * 64];  // 4KB, wave-private
  const int lane = threadIdx.x;
  const int lr = lane & 15, lg = lane >> 4;

  const int bid = blockIdx.x;
  const int xcd = bid & 7;
  const int rdec = bid >> 3;      // 0..255
  const int slot = rdec >> 6;     // 0..3
  const int rank = rdec & 63;     // 0..63
  const int bh = slot * 8 + xcd;
  const int b = bh >> 4, h = bh & 15;
  const int c = 63 - rank;        // LPT: largest chunk first
  const int QR = c * 32;          // first of this wave's 32 Q rows
  const int nt = (c >> 1) + 1;    // causal KV tiles (64 wide)

  const __bf16* Qb = Q + (size_t)bh * SEQ * DK;
  const __bf16* Kb = Kt + (size_t)bh * SEQ * DK;
  const __bf16* Vb = Vt + (size_t)bh * DK * SEQ;
  const float* pm = pmask + (size_t)b * SEQ;
  const float SCL = 0.125f * 1.44269504f;   // 1/sqrt(dk) * log2(e)
  const float L2E = 1.44269504f;

  // Q B-frags: rg selects row group (QR+rg*16+lr), kk selects k-slice
  bf16x8 qf[2][2];
  #pragma unroll
  for (int rg = 0; rg < 2; ++rg)
    #pragma unroll
    for (int kk = 0; kk < 2; ++kk)
      qf[rg][kk] = *(const bf16x8*)&Qb[(size_t)(QR + rg * 16 + lr) * DK + kk * 32 + lg * 8];

  float mrow[2] = {-1e30f, -1e30f}, lrw[2] = {0.f, 0.f};  // q-row rg*16+lr (log2)
  f32x4 oacc[2][4] = {};   // [rg][og]: row q=rg*16+lg*4+r, col d=og*16+lr

  for (int t = 0; t < nt; ++t) {
    // ---- S^T = K Q^T: K-frags shared by both row groups ----
    f32x4 sc[2][4];
    #pragma unroll
    for (int g = 0; g < 4; ++g) {
      const __bf16* krow = &Kb[(size_t)(t * 64 + g * 16 + lr) * DK + lg * 8];
      const bf16x8 kf0 = *(const bf16x8*)krow;
      const bf16x8 kf1 = *(const bf16x8*)(krow + 32);
      f32x4 a0 = {}, a1 = {};
      a0 = __builtin_amdgcn_mfma_f32_16x16x32_bf16(kf0, qf[0][0], a0, 0, 0, 0);
      a0 = __builtin_amdgcn_mfma_f32_16x16x32_bf16(kf1, qf[0][1], a0, 0, 0, 0);
      a1 = __builtin_amdgcn_mfma_f32_16x16x32_bf16(kf0, qf[1][0], a1, 0, 0, 0);
      a1 = __builtin_amdgcn_mfma_f32_16x16x32_bf16(kf1, qf[1][1], a1, 0, 0, 0);
      sc[0][g] = a0;   // sc[rg][g][r] = S[q=QR+rg*16+lr][kv=t*64+g*16+lg*4+r]
      sc[1][g] = a1;
    }
    // ---- scale + padding mask + causal mask (log2 domain) ----
    const bool edge = (t == nt - 1);
    #pragma unroll
    for (int g = 0; g < 4; ++g) {
      const float4 pmv = *(const float4*)&pm[t * 64 + g * 16 + lg * 4];
      const float pmf[4] = {pmv.x, pmv.y, pmv.z, pmv.w};
      #pragma unroll
      for (int rg = 0; rg < 2; ++rg)
        #pragma unroll
        for (int r = 0; r < 4; ++r) {
          float s = sc[rg][g][r] * SCL + pmf[r] * L2E;
          if (edge && (t * 64 + g * 16 + lg * 4 + r > QR + rg * 16 + lr)) s = -1e30f;
          sc[rg][g][r] = s;
        }
    }
    // ---- online softmax per row group (lane owns full row) ----
    float alpha[2];
    #pragma unroll
    for (int rg = 0; rg < 2; ++rg) {
      float pmax = sc[rg][0][0];
      #pragma unroll
      for (int g = 0; g < 4; ++g)
        #pragma unroll
        for (int r = 0; r < 4; ++r) pmax = fmaxf(pmax, sc[rg][g][r]);
      pmax = fmaxf(pmax, __shfl_xor(pmax, 16, 64));
      pmax = fmaxf(pmax, __shfl_xor(pmax, 32, 64));
      const float mnew = fmaxf(mrow[rg], pmax);
      alpha[rg] = exp2f(mrow[rg] - mnew);
      mrow[rg] = mnew;
      float psum = 0.f;
      #pragma unroll
      for (int g = 0; g < 4; ++g)
        #pragma unroll
        for (int r = 0; r < 4; ++r) {
          float p = exp2f(sc[rg][g][r] - mnew);
          sc[rg][g][r] = p;
          psum += p;
        }
      psum += __shfl_xor(psum, 16, 64);
      psum += __shfl_xor(psum, 32, 64);
      lrw[rg] = lrw[rg] * alpha[rg] + psum;
    }
    // ---- rescale O rows (q = rg*16 + lg*4+r) ----
    #pragma unroll
    for (int rg = 0; rg < 2; ++rg)
      #pragma unroll
      for (int r = 0; r < 4; ++r) {
        const float av = __shfl(alpha[rg], lg * 4 + r, 64);
        #pragma unroll
        for (int og = 0; og < 4; ++og) oacc[rg][og][r] *= av;
      }
    // ---- P -> wave-private LDS (bf16, XOR swizzle (row&7)<<4; row&7 == lr&7) ----
    #pragma unroll
    for (int rg = 0; rg < 2; ++rg)
      #pragma unroll
      for (int g = 0; g < 4; ++g) {
        bf16x4 pk = { (__bf16)sc[rg][g][0], (__bf16)sc[rg][g][1],
                      (__bf16)sc[rg][g][2], (__bf16)sc[rg][g][3] };
        const int byteoff = (rg * 16 + lr) * 128 + ((g * 32 + lg * 8) ^ ((lr & 7) << 4));
        *(bf16x4*)((char*)plds + byteoff) = pk;
      }
    // ---- PV: O += P V. V-frags shared by both row groups ----
    #pragma unroll
    for (int kk = 0; kk < 2; ++kk) {
      const int sw = (kk * 64 + lg * 16) ^ ((lr & 7) << 4);
      const bf16x8 pa0 = *(const bf16x8*)((char*)plds + lr * 128 + sw);
      const bf16x8 pa1 = *(const bf16x8*)((char*)plds + (16 + lr) * 128 + sw);
      #pragma unroll
      for (int og = 0; og < 4; ++og) {
        const bf16x8 vf = *(const bf16x8*)&Vb[(size_t)(og * 16 + lr) * SEQ + t * 64 + kk * 32 + lg * 8];
        oacc[0][og] = __builtin_amdgcn_mfma_f32_16x16x32_bf16(pa0, vf, oacc[0][og], 0, 0, 0);
        oacc[1][og] = __builtin_amdgcn_mfma_f32_16x16x32_bf16(pa1, vf, oacc[1][og], 0, 0, 0);
      }
    }
  }

  // ---- epilogue: normalize, write O [B,S,H*DK] ----
  #pragma unroll
  for (int rg = 0; rg < 2; ++rg)
    #pragma unroll
    for (int r = 0; r < 4; ++r) {
      const float lsh = __shfl(lrw[rg], lg * 4 + r, 64);
      const float inv = 1.f / lsh;
      const int row = QR + rg * 16 + lg * 4 + r;
      #pragma unroll
      for (int og = 0; og < 4; ++og)
        O[((size_t)b * SEQ + row) * DMODEL + h * DK + og * 16 + lr] = (__bf16)(oacc[rg][og][r] * inv);
    }
}

extern "C" void kernel_launch(void* const* d_in, const int* in_sizes, int n_in,
                              void* d_out, int out_size, void* d_ws, size_t ws_size,
                              hipStream_t stream) {
  (void)in_sizes; (void)n_in; (void)out_size; (void)ws_size;
  const float* query = (const float*)d_in[0];
  const float* key   = (const float*)d_in[1];
  const float* value = (const float*)d_in[2];
  const float* pmask = (const float*)d_in[3];
  const float* w_q = (const float*)d_in[5];
  const float* w_k = (const float*)d_in[6];
  const float* w_v = (const float*)d_in[7];
  const float* w_o = (const float*)d_in[8];
  const float* b_q = (const float*)d_in[9];
  const float* b_k = (const float*)d_in[10];
  const float* b_v = (const float*)d_in[11];
  const float* b_o = (const float*)d_in[12];

  __bf16* ws = (__bf16*)d_ws;
  const size_t WSZ = (size_t)DMODEL * DMODEL;  // 1M elems
  const size_t XSZ = (size_t)MTOT * DMODEL;    // 4M elems
  __bf16* WTq = ws;
  __bf16* WTk = WTq + WSZ;
  __bf16* WTv = WTk + WSZ;
  __bf16* WTo = WTv + WSZ;
  __bf16* Xq  = WTo + WSZ;
  __bf16* Xk  = Xq + XSZ;
  __bf16* Xv  = Xk + XSZ;
  __bf16* Qh  = Xv + XSZ;
  __bf16* Kh  = Qh + XSZ;
  __bf16* Vh  = Kh + XSZ;
  __bf16* Oh  = Xq;  // alias: Xq dead after q projection

  dim3 blk(256);
  k_cvt3<<<dim3(4096, 3), blk, 0, stream>>>(query, key, value, Xq, Xk, Xv, (int)(XSZ / 4));
  k_transpose4<<<dim3(32, 32, 4), blk, 0, stream>>>(w_q, w_k, w_v, w_o, WTq, WTk, WTv, WTo);

  k_gemm_qkv<<<dim3(8, 32, 3), blk, 0, stream>>>(Xq, Xk, Xv, WTq, WTk, WTv,
                                                 b_q, b_k, b_v, Qh, Kh, Vh);

  k_attn<<<dim3(2048), 64, 0, stream>>>(Qh, Kh, Vh, pmask, Oh);

  k_gemm_out<<<dim3(8, 32), blk, 0, stream>>>(Oh, WTo, b_o, (float*)d_out);
}